// Round 6
// baseline (434.528 us; speedup 1.0000x reference)
//
#include <hip/hip_runtime.h>
#include <hip/hip_bf16.h>
#include <math.h>

typedef unsigned short ushort;
typedef __attribute__((ext_vector_type(4))) float f32x4;
typedef __attribute__((ext_vector_type(8))) short s16x8;
typedef __attribute__((ext_vector_type(4))) short s16x4;
typedef __attribute__((ext_vector_type(4))) ushort u16x4;

#define H_    64
#define W_    64
#define DIM   160
#define HEADS 5
#define KD    32
#define WS    14
#define NTOK  196
#define NWIN  400
#define HIDDEN 640
#define EPS   1e-5f
#define NROW  (NWIN*NTOK)    // 78400
#define BATCH 16
#define L_    (H_*W_)
#define MROW  (BATCH*L_)     // 65536

#if __has_builtin(__builtin_amdgcn_exp2f)
#define EXP2(x) __builtin_amdgcn_exp2f(x)
#else
#define EXP2(x) exp2f(x)
#endif

__device__ __forceinline__ ushort f2bfbits(float f) {
    unsigned u = __float_as_uint(f);
    unsigned r = (u + 0x7fffu + ((u >> 16) & 1u)) >> 16;
    return (ushort)r;
}

// ---------------------------------------------------------------- pre kernel
__global__ __launch_bounds__(256) void pre_kernel(
    const float* __restrict__ qkv_w, const float* __restrict__ proj_w,
    const float* __restrict__ fc1_w, const float* __restrict__ fc2_w,
    const float* __restrict__ conv_w, const float* __restrict__ bn_g,
    const float* __restrict__ abias, const int* __restrict__ bidx,
    ushort* __restrict__ wb, float* __restrict__ cwT,
    float* __restrict__ biasT, int n_off)
{
    const int gid = blockIdx.x * 256 + threadIdx.x;
    if (gid < 19200) {
        float4 v = ((const float4*)qkv_w)[gid];
        u16x4 o = { f2bfbits(v.x), f2bfbits(v.y), f2bfbits(v.z), f2bfbits(v.w) };
        *(u16x4*)(wb + gid * 4) = o;
    } else if (gid < 25600) {
        const int i = gid - 19200;
        float4 v = ((const float4*)proj_w)[i];
        u16x4 o = { f2bfbits(v.x), f2bfbits(v.y), f2bfbits(v.z), f2bfbits(v.w) };
        *(u16x4*)(wb + 76800 + i * 4) = o;
    } else if (gid < 51200) {
        const int i = gid - 25600;
        float4 v = ((const float4*)fc1_w)[i];
        u16x4 o = { f2bfbits(v.x), f2bfbits(v.y), f2bfbits(v.z), f2bfbits(v.w) };
        *(u16x4*)(wb + 102400 + i * 4) = o;
    } else if (gid < 76800) {
        const int i = gid - 51200;
        float4 v = ((const float4*)fc2_w)[i];
        u16x4 o = { f2bfbits(v.x), f2bfbits(v.y), f2bfbits(v.z), f2bfbits(v.w) };
        *(u16x4*)(wb + 204800 + i * 4) = o;
    } else if (gid < 77160) {
        const int i = gid - 76800;
        const int t = i / 40, c4 = (i % 40) * 4;
#pragma unroll
        for (int j = 0; j < 4; ++j) {
            const int c = c4 + j;
            cwT[t * DIM + c] = conv_w[c * 9 + t] * bn_g[c] * rsqrtf(1.0f + EPS);
        }
    } else if (gid < 269240) {
        const int i = gid - 77160;
        const int h = i / (NTOK * NTOK), r = i % (NTOK * NTOK);
        const int q = r / NTOK, k = r % NTOK;
        biasT[i] = abias[h * n_off + bidx[q * NTOK + k]] * 5.656854249492381f;
    }
}

// ---------------------------------------------------------------- MFMA GEMM
// C[m,n] = sum_k A[m,k] * Wb[n,k] + bias[n].  K == 160 fixed.
// Weight panel (160 x 160) staged in LDS once; A entirely in registers;
// zero barriers in the MFMA loop.
// ASRC: 0 = A is bf16 [M][160]; 1 = A is fp32 x with window-gather + LN1.
// EPI:  0 = store bf16; 1 = crop/scatter + residual fp32.
template <int ASRC, int EPI>
__global__ __launch_bounds__(256) void gemm_mfma(
    const void* __restrict__ Av, const ushort* __restrict__ Wb,
    const float* __restrict__ bias, void* __restrict__ Cv,
    const float* __restrict__ extra, const float* __restrict__ lng,
    const float* __restrict__ lnb, int M, int N)
{
    __shared__ ushort Bs[160][164];
    const int tid = threadIdx.x;
    const int wv = tid >> 6, ln = tid & 63;
    const int g = ln >> 4, l15 = ln & 15;
    const int m0 = blockIdx.y * 128, n0 = blockIdx.x * 160;

    // stage weight panel (L2-resident)
    for (int e = tid; e < 160 * 20; e += 256) {
        const int row = e / 20, part = e % 20;
        *(int4*)&Bs[row][part * 8] =
            *(const int4*)(Wb + (size_t)(n0 + row) * 160 + part * 8);
    }

    s16x8 a[2][5];
    if (ASRC == 0) {
        const ushort* A = (const ushort*)Av;
#pragma unroll
        for (int mt = 0; mt < 2; ++mt) {
            int am = m0 + wv * 32 + mt * 16 + l15; if (am >= M) am = M - 1;
            const ushort* ap = A + (size_t)am * 160 + g * 8;
#pragma unroll
            for (int s = 0; s < 5; ++s) a[mt][s] = *(const s16x8*)(ap + s * 32);
        }
    } else {
        const float* X = (const float*)Av;
#pragma unroll
        for (int mt = 0; mt < 2; ++mt) {
            int am = m0 + wv * 32 + mt * 16 + l15; if (am >= M) am = M - 1;
            const int win = am / NTOK, tok = am % NTOK;
            const int bb = win / 25, wr = (win % 25) / 5, wc = win % 5;
            const int gh = wr * WS + tok / WS, gw = wc * WS + tok % WS;
            const bool valid = (gh < H_) && (gw < W_);
            const float* xp = X + ((size_t)(bb << 12) + (gh << 6) + gw) * DIM + g * 8;
            float4 va[10];
            float vsum = 0.f, vsq = 0.f;
#pragma unroll
            for (int s = 0; s < 5; ++s) {
                float4 p0 = make_float4(0.f, 0.f, 0.f, 0.f);
                float4 p1 = make_float4(0.f, 0.f, 0.f, 0.f);
                if (valid) {
                    p0 = *(const float4*)(xp + s * 32);
                    p1 = *(const float4*)(xp + s * 32 + 4);
                }
                va[s * 2] = p0; va[s * 2 + 1] = p1;
                vsum += (p0.x + p0.y) + (p0.z + p0.w) + (p1.x + p1.y) + (p1.z + p1.w);
                vsq  += (p0.x*p0.x + p0.y*p0.y) + (p0.z*p0.z + p0.w*p0.w)
                      + (p1.x*p1.x + p1.y*p1.y) + (p1.z*p1.z + p1.w*p1.w);
            }
            vsum += __shfl_xor(vsum, 16); vsum += __shfl_xor(vsum, 32);
            vsq  += __shfl_xor(vsq, 16);  vsq  += __shfl_xor(vsq, 32);
            const float mean = vsum * (1.0f / DIM);
            const float rs = rsqrtf(vsq * (1.0f / DIM) - mean * mean + EPS);
#pragma unroll
            for (int s = 0; s < 5; ++s) {
                const float4 g0 = *(const float4*)(lng + s * 32 + g * 8);
                const float4 g1 = *(const float4*)(lng + s * 32 + g * 8 + 4);
                const float4 b0 = *(const float4*)(lnb + s * 32 + g * 8);
                const float4 b1 = *(const float4*)(lnb + s * 32 + g * 8 + 4);
                const float4 p0 = va[s * 2], p1 = va[s * 2 + 1];
                ushort o[8];
                o[0] = f2bfbits((p0.x - mean) * rs * g0.x + b0.x);
                o[1] = f2bfbits((p0.y - mean) * rs * g0.y + b0.y);
                o[2] = f2bfbits((p0.z - mean) * rs * g0.z + b0.z);
                o[3] = f2bfbits((p0.w - mean) * rs * g0.w + b0.w);
                o[4] = f2bfbits((p1.x - mean) * rs * g1.x + b1.x);
                o[5] = f2bfbits((p1.y - mean) * rs * g1.y + b1.y);
                o[6] = f2bfbits((p1.z - mean) * rs * g1.z + b1.z);
                o[7] = f2bfbits((p1.w - mean) * rs * g1.w + b1.w);
                a[mt][s] = *(const s16x8*)o;
            }
        }
    }
    __syncthreads();

    f32x4 acc[2][10] = {};
#pragma unroll
    for (int j = 0; j < 5; ++j) {
#pragma unroll
        for (int nt = 0; nt < 10; ++nt) {
            const s16x8 bf = *(const s16x8*)&Bs[nt * 16 + l15][j * 32 + g * 8];
            acc[0][nt] = __builtin_amdgcn_mfma_f32_16x16x32_bf16(a[0][j], bf, acc[0][nt], 0, 0, 0);
            acc[1][nt] = __builtin_amdgcn_mfma_f32_16x16x32_bf16(a[1][j], bf, acc[1][nt], 0, 0, 0);
        }
    }

#pragma unroll
    for (int mt = 0; mt < 2; ++mt) {
#pragma unroll
        for (int nt = 0; nt < 10; ++nt) {
            const int n = n0 + nt * 16 + l15;
            const float bn = bias[n];
#pragma unroll
            for (int r = 0; r < 4; ++r) {
                const int m = m0 + wv * 32 + mt * 16 + g * 4 + r;
                if (m >= M) continue;
                const float val = acc[mt][nt][r] + bn;
                if (EPI == 0) {
                    ((ushort*)Cv)[(size_t)m * N + n] = f2bfbits(val);
                } else {
                    const int win = m / NTOK, tok = m % NTOK;
                    const int bb = win / 25, wr = (win % 25) / 5, wc = win % 5;
                    const int gh = wr * WS + tok / WS, gw = wc * WS + tok % WS;
                    if (gh < H_ && gw < W_) {
                        const size_t off = ((size_t)bb * L_ + (size_t)gh * W_ + gw) * DIM + n;
                        ((float*)Cv)[off] = extra[off] + val;
                    }
                }
            }
        }
    }
}

// ---------------------------------------------------------------- fused MLP
// out = x2 + fc2(gelu(fc1(LN2(x2))))  -- h never touches HBM.
// 64 rows/block, 4 waves x 16 rows. Hidden split into 4 chunks of 160.
__global__ __launch_bounds__(256) void mlp_fused(
    float* xo, const ushort* __restrict__ wb1, const ushort* __restrict__ wb2,
    const float* __restrict__ fc1_b, const float* __restrict__ fc2_b,
    const float* __restrict__ lng, const float* __restrict__ lnb)
{
    __shared__ ushort Bs[160][164];
    __shared__ ushort hS[4][16][164];
    const int tid = threadIdx.x;
    const int wv = tid >> 6, ln = tid & 63;
    const int g = ln >> 4, l15 = ln & 15;
    const int b0 = blockIdx.x * 64;
    const int row = b0 + wv * 16 + l15;

    // ---- LN2 in registers
    const float* xp = xo + (size_t)row * DIM + g * 8;
    float4 va[10];
    float vsum = 0.f, vsq = 0.f;
#pragma unroll
    for (int s = 0; s < 5; ++s) {
        const float4 p0 = *(const float4*)(xp + s * 32);
        const float4 p1 = *(const float4*)(xp + s * 32 + 4);
        va[s * 2] = p0; va[s * 2 + 1] = p1;
        vsum += (p0.x + p0.y) + (p0.z + p0.w) + (p1.x + p1.y) + (p1.z + p1.w);
        vsq  += (p0.x*p0.x + p0.y*p0.y) + (p0.z*p0.z + p0.w*p0.w)
              + (p1.x*p1.x + p1.y*p1.y) + (p1.z*p1.z + p1.w*p1.w);
    }
    vsum += __shfl_xor(vsum, 16); vsum += __shfl_xor(vsum, 32);
    vsq  += __shfl_xor(vsq, 16);  vsq  += __shfl_xor(vsq, 32);
    const float mean = vsum * (1.0f / DIM);
    const float rs = rsqrtf(vsq * (1.0f / DIM) - mean * mean + EPS);
    s16x8 a1[5];
#pragma unroll
    for (int s = 0; s < 5; ++s) {
        const float4 g0 = *(const float4*)(lng + s * 32 + g * 8);
        const float4 g1 = *(const float4*)(lng + s * 32 + g * 8 + 4);
        const float4 bb0 = *(const float4*)(lnb + s * 32 + g * 8);
        const float4 bb1 = *(const float4*)(lnb + s * 32 + g * 8 + 4);
        const float4 p0 = va[s * 2], p1 = va[s * 2 + 1];
        ushort o[8];
        o[0] = f2bfbits((p0.x - mean) * rs * g0.x + bb0.x);
        o[1] = f2bfbits((p0.y - mean) * rs * g0.y + bb0.y);
        o[2] = f2bfbits((p0.z - mean) * rs * g0.z + bb0.z);
        o[3] = f2bfbits((p0.w - mean) * rs * g0.w + bb0.w);
        o[4] = f2bfbits((p1.x - mean) * rs * g1.x + bb1.x);
        o[5] = f2bfbits((p1.y - mean) * rs * g1.y + bb1.y);
        o[6] = f2bfbits((p1.z - mean) * rs * g1.z + bb1.z);
        o[7] = f2bfbits((p1.w - mean) * rs * g1.w + bb1.w);
        a1[s] = *(const s16x8*)o;
    }

    f32x4 oacc[10] = {};
    for (int c = 0; c < 4; ++c) {
        __syncthreads();   // previous chunk's Bs reads complete
        for (int e = tid; e < 160 * 20; e += 256) {
            const int r_ = e / 20, p_ = e % 20;
            *(int4*)&Bs[r_][p_ * 8] =
                *(const int4*)(wb1 + (size_t)(c * 160 + r_) * 160 + p_ * 8);
        }
        __syncthreads();

        f32x4 hacc[10] = {};
#pragma unroll
        for (int j = 0; j < 5; ++j) {
#pragma unroll
            for (int nt = 0; nt < 10; ++nt) {
                const s16x8 bf = *(const s16x8*)&Bs[nt * 16 + l15][j * 32 + g * 8];
                hacc[nt] = __builtin_amdgcn_mfma_f32_16x16x32_bf16(a1[j], bf, hacc[nt], 0, 0, 0);
            }
        }
        // GELU + wave-private LDS stage of h (bf16)
#pragma unroll
        for (int nt = 0; nt < 10; ++nt) {
            const float hb = fc1_b[c * 160 + nt * 16 + l15];
#pragma unroll
            for (int r = 0; r < 4; ++r) {
                const float val = hacc[nt][r] + hb;
                const float t = EXP2(-2.302259756f * fmaf(0.044715f * val * val, val, val));
                const float ge = val * __builtin_amdgcn_rcpf(1.0f + t);
                hS[wv][g * 4 + r][nt * 16 + l15] = f2bfbits(ge);
            }
        }
        __syncthreads();   // all waves done reading W1 panel
        for (int e = tid; e < 160 * 20; e += 256) {
            const int r_ = e / 20, p_ = e % 20;
            *(int4*)&Bs[r_][p_ * 8] =
                *(const int4*)(wb2 + (size_t)r_ * HIDDEN + c * 160 + p_ * 8);
        }
        __syncthreads();
#pragma unroll
        for (int j = 0; j < 5; ++j) {
            const s16x8 a2 = *(const s16x8*)&hS[wv][l15][j * 32 + g * 8];
#pragma unroll
            for (int nt = 0; nt < 10; ++nt) {
                const s16x8 bf = *(const s16x8*)&Bs[nt * 16 + l15][j * 32 + g * 8];
                oacc[nt] = __builtin_amdgcn_mfma_f32_16x16x32_bf16(a2, bf, oacc[nt], 0, 0, 0);
            }
        }
    }

    // ---- epilogue: residual add, in-place (rows are block-exclusive)
#pragma unroll
    for (int nt = 0; nt < 10; ++nt) {
        const int n = nt * 16 + l15;
        const float bn = fc2_b[n];
#pragma unroll
        for (int r = 0; r < 4; ++r) {
            const int m = b0 + wv * 16 + g * 4 + r;
            const size_t off = (size_t)m * DIM + n;
            const float res = xo[off];
            xo[off] = res + oacc[nt][r] + bn;
        }
    }
}

// ---------------------------------------------------------------- attention
__global__ __launch_bounds__(256) void attn_mfma_kernel(
    const ushort* __restrict__ qkv, const float* __restrict__ biasT,
    ushort* __restrict__ out)
{
    __shared__ ushort Ks[208][40];
    __shared__ ushort VT[32][212];
    const int win = blockIdx.x / HEADS;
    const int h   = blockIdx.x % HEADS;
    const int tid = threadIdx.x;
    const size_t base = (size_t)win * NTOK;
    const ushort* qbase = qkv + base * 480 + h * 96;

    for (int e = tid; e < 208 * 4; e += 256) {
        const int row = e >> 2, part = e & 3;
        const int gr = row < NTOK ? row : NTOK - 1;
        *(int4*)&Ks[row][part * 8] = *(const int4*)(qbase + (size_t)gr * 480 + 32 + part * 8);
    }
    for (int e = tid; e < NTOK * 4; e += 256) {
        const int key = e >> 2, part = e & 3;
        int4 p = *(const int4*)(qbase + (size_t)key * 480 + 64 + part * 8);
        const ushort* u = (const ushort*)&p;
#pragma unroll
        for (int j = 0; j < 8; ++j) VT[part * 8 + j][key] = u[j];
    }
    for (int e = tid; e < 12 * 32; e += 256) VT[e & 31][NTOK + (e >> 5)] = 0;
    __syncthreads();

    const int wv = tid >> 6, ln = tid & 63, g = ln >> 4, l15 = ln & 15;
    const float cs = 0.17677669529663687f * 1.4426950408889634f;  // scale*log2e

    for (int qt = wv; qt < 13; qt += 4) {
        const int qr = qt * 16 + l15;
        const int qc = qr < NTOK ? qr : NTOK - 1;
        const s16x8 qf = *(const s16x8*)(qbase + (size_t)qc * 480 + g * 8);
        const float* bq = biasT + ((size_t)h * NTOK + qc) * NTOK;

        f32x4 S[13];
#pragma unroll
        for (int kt = 0; kt < 13; ++kt)
            S[kt] = *(const f32x4*)(bq + kt * 16 + g * 4);
#pragma unroll
        for (int kt = 0; kt < 13; ++kt) {
            const s16x8 kf = *(const s16x8*)&Ks[kt * 16 + l15][g * 8];
            S[kt] = __builtin_amdgcn_mfma_f32_16x16x32_bf16(kf, qf, S[kt], 0, 0, 0);
        }
        float mx = -1e30f;
#pragma unroll
        for (int kt = 0; kt < 13; ++kt) {
            const int kb = kt * 16 + g * 4;
#pragma unroll
            for (int r = 0; r < 4; ++r) {
                const float sv = (kb + r < NTOK) ? S[kt][r] * cs : -1e30f;
                S[kt][r] = sv;
                mx = fmaxf(mx, sv);
            }
        }
        mx = fmaxf(mx, __shfl_xor(mx, 16));
        mx = fmaxf(mx, __shfl_xor(mx, 32));

        float sum = 0.f;
        s16x4 P[13];
#pragma unroll
        for (int kt = 0; kt < 13; ++kt) {
            const float p0 = EXP2(S[kt][0] - mx);
            const float p1 = EXP2(S[kt][1] - mx);
            const float p2 = EXP2(S[kt][2] - mx);
            const float p3 = EXP2(S[kt][3] - mx);
            sum += (p0 + p1) + (p2 + p3);
            P[kt] = (s16x4){ (short)f2bfbits(p0), (short)f2bfbits(p1),
                             (short)f2bfbits(p2), (short)f2bfbits(p3) };
        }
        sum += __shfl_xor(sum, 16);
        sum += __shfl_xor(sum, 32);

        f32x4 o0 = {0.f,0.f,0.f,0.f}, o1 = {0.f,0.f,0.f,0.f};
#pragma unroll
        for (int kt = 0; kt < 13; ++kt) {
            const s16x4 vf0 = *(const s16x4*)&VT[l15][kt * 16 + g * 4];
            const s16x4 vf1 = *(const s16x4*)&VT[16 + l15][kt * 16 + g * 4];
            o0 = __builtin_amdgcn_mfma_f32_16x16x16bf16_1k(vf0, P[kt], o0, 0, 0, 0);
            o1 = __builtin_amdgcn_mfma_f32_16x16x16bf16_1k(vf1, P[kt], o1, 0, 0, 0);
        }
        if (qr < NTOK) {
            const float inv = 1.0f / sum;
            ushort* op = out + (base + qr) * DIM + h * KD;
            u16x4 w0 = { f2bfbits(o0[0] * inv), f2bfbits(o0[1] * inv),
                         f2bfbits(o0[2] * inv), f2bfbits(o0[3] * inv) };
            u16x4 w1 = { f2bfbits(o1[0] * inv), f2bfbits(o1[1] * inv),
                         f2bfbits(o1[2] * inv), f2bfbits(o1[3] * inv) };
            *(u16x4*)(op + g * 4)      = w0;
            *(u16x4*)(op + 16 + g * 4) = w1;
        }
    }
}

// ---------------------------------------------------------------- dw conv + BN
__global__ __launch_bounds__(256) void dwconv_bn_kernel(
    const float* __restrict__ xin, const float* __restrict__ cwT,
    const float* __restrict__ bnb, float* __restrict__ xout)
{
    const int gid = blockIdx.x * 256 + threadIdx.x;   // MROW*40
    const int pos = gid / 40, c4 = (gid % 40) * 4;
    const int bb = pos >> 12, hw = pos & 4095;
    const int hh = hw >> 6, ww = hw & 63;
    float4 acc = *(const float4*)&bnb[c4];
#pragma unroll
    for (int kh = -1; kh <= 1; ++kh) {
        const int ih = hh + kh;
        if (ih < 0 || ih >= H_) continue;
#pragma unroll
        for (int kw = -1; kw <= 1; ++kw) {
            const int iw = ww + kw;
            if (iw < 0 || iw >= W_) continue;
            const float4 xv = *(const float4*)&xin[((size_t)(bb << 12) + (ih << 6) + iw) * DIM + c4];
            const float4 wv = *(const float4*)&cwT[((kh + 1) * 3 + (kw + 1)) * DIM + c4];
            acc.x = fmaf(xv.x, wv.x, acc.x);
            acc.y = fmaf(xv.y, wv.y, acc.y);
            acc.z = fmaf(xv.z, wv.z, acc.z);
            acc.w = fmaf(xv.w, wv.w, acc.w);
        }
    }
    *(float4*)&xout[(size_t)pos * DIM + c4] = acc;
}

// ---------------------------------------------------------------- launch
extern "C" void kernel_launch(void* const* d_in, const int* in_sizes, int n_in,
                              void* d_out, int out_size, void* d_ws, size_t ws_size,
                              hipStream_t stream)
{
    const float* x      = (const float*)d_in[0];
    const float* ln1_g  = (const float*)d_in[1];
    const float* ln1_b  = (const float*)d_in[2];
    const float* qkv_w  = (const float*)d_in[3];
    const float* qkv_b  = (const float*)d_in[4];
    const float* proj_w = (const float*)d_in[5];
    const float* proj_b = (const float*)d_in[6];
    const float* abias  = (const float*)d_in[7];
    const float* conv_w = (const float*)d_in[8];
    const float* bn_g   = (const float*)d_in[9];
    const float* bn_b   = (const float*)d_in[10];
    const float* ln2_g  = (const float*)d_in[11];
    const float* ln2_b  = (const float*)d_in[12];
    const float* fc1_w  = (const float*)d_in[13];
    const float* fc1_b  = (const float*)d_in[14];
    const float* fc2_w  = (const float*)d_in[15];
    const float* fc2_b  = (const float*)d_in[16];
    const int*   bidx   = (const int*)d_in[17];
    const int    n_off  = in_sizes[7] / HEADS;

    char* ws = (char*)d_ws;
    // [0,           75,264,000)  qkv  bf16 78400x480
    // [75,264,000, 100,352,000)  ao   bf16 78400x160
    // [100,352,000,142,295,040)  x1   f32  65536x160
    // [142,295,040,143,063,360)  biasT f32 5x196x196
    // [143,063,360,143,677,760)  wb   bf16 weights (qkv|proj|fc1|fc2)
    // [143,677,760,143,683,520)  cwT  f32 9x160 (BN-folded)
    ushort* qkv   = (ushort*)(ws);
    ushort* ao    = (ushort*)(ws + 75264000);
    float*  x1    = (float*)(ws + 100352000);
    float*  biasT = (float*)(ws + 142295040);
    ushort* wb    = (ushort*)(ws + 143063360);
    float*  cwT   = (float*)(ws + 143677760);
    float*  x2    = (float*)d_out;

    pre_kernel<<<dim3(1052), dim3(256), 0, stream>>>(
        qkv_w, proj_w, fc1_w, fc2_w, conv_w, bn_g, abias, bidx, wb, cwT, biasT, n_off);

    // LN1 fused into qkv GEMM (window-gather from x)
    gemm_mfma<1, 0><<<dim3(3, 613), dim3(256), 0, stream>>>(
        (const void*)x, wb, qkv_b, (void*)qkv, nullptr, ln1_g, ln1_b, NROW, 480);

    attn_mfma_kernel<<<dim3(NWIN * HEADS), dim3(256), 0, stream>>>(qkv, biasT, ao);

    gemm_mfma<0, 1><<<dim3(1, 613), dim3(256), 0, stream>>>(
        (const void*)ao, wb + 76800, proj_b, (void*)x1, x, nullptr, nullptr, NROW, 160);

    dwconv_bn_kernel<<<dim3(MROW * 40 / 256), dim3(256), 0, stream>>>(
        x1, cwT, bn_b, x2);

    // LN2 + fc1 + GELU + fc2 + residual, h stays on-chip
    mlp_fused<<<dim3(MROW / 64), dim3(256), 0, stream>>>(
        x2, wb + 102400, wb + 204800, fc1_b, fc2_b, ln2_g, ln2_b);
}